// Round 14
// baseline (459.324 us; speedup 1.0000x reference)
//
#include <hip/hip_runtime.h>

typedef unsigned short u16;
typedef __attribute__((ext_vector_type(8))) short bf16x8;
typedef __attribute__((ext_vector_type(4))) float f32x4;

#define SC_LOG2E 0.18033688011112043f  // 0.125 * log2(e)
#define MB_LOG2E 17.31234049066756f    // 12 * log2(e)  (static softmax max; logits hard-bounded << 88)

__device__ __forceinline__ float b2f(u16 u) {
  union { unsigned int i; float f; } v; v.i = ((unsigned int)u) << 16; return v.f;
}
__device__ __forceinline__ u16 f2b(float f) {
  unsigned int x = __float_as_uint(f);
  unsigned int r = (x + 0x7fffu + ((x >> 16) & 1u)) >> 16;
  return (u16)r;
}

// async global->LDS, 16B per lane; lds base must be wave-uniform, lane l lands at base + l*16
#define GLOAD_LDS16(g, l)                                                              \
  __builtin_amdgcn_global_load_lds((const __attribute__((address_space(1))) void*)(g), \
                                   (__attribute__((address_space(3))) void*)(l), 16, 0, 0)

// ------- prep: 4 weight transposes + LayerNorm1, ONE launch -------------------------
// blocks [0,3072): transpose jobs; [3072,11264): ln1 rows. Per-block uniform branch.
struct TJob { const float* in; u16* out; int K, N, nbx, nblocks; };

__global__ __launch_bounds__(256) void prep_kernel(TJob j0, TJob j1, TJob j2, TJob j3,
                                                   const float* __restrict__ xv,
                                                   const float* __restrict__ g,
                                                   const float* __restrict__ bb,
                                                   u16* __restrict__ o) {
  const int tid = threadIdx.x;
  if (blockIdx.x < 3072) {
    int bid = blockIdx.x;
    TJob j = j0;
    if (bid >= j.nblocks) { bid -= j.nblocks; j = j1; }
    if (bid >= j.nblocks) { bid -= j.nblocks; j = j2; }
    if (bid >= j.nblocks) { bid -= j.nblocks; j = j3; }
    const int n0 = (bid % j.nbx) * 64, k0 = (bid / j.nbx) * 64;
    const int N = j.N, K = j.K;
    const float* __restrict__ in = j.in;
    u16* __restrict__ out = j.out;

    __shared__ float tile[64][65];
#pragma unroll
    for (int it = 0; it < 4; ++it) {
      int lin = it * 256 + tid;
      int r = lin >> 4, c4 = (lin & 15) * 4;
      float4 v = *(const float4*)&in[(size_t)(k0 + r) * N + n0 + c4];
      tile[r][c4 + 0] = v.x; tile[r][c4 + 1] = v.y;
      tile[r][c4 + 2] = v.z; tile[r][c4 + 3] = v.w;
    }
    __syncthreads();
#pragma unroll
    for (int it = 0; it < 2; ++it) {
      int lin = it * 256 + tid;
      int r = lin >> 3, c8 = (lin & 7) * 8;  // r = n-index, c8 = k-block
      u16 tmp[8];
#pragma unroll
      for (int jj = 0; jj < 8; ++jj) tmp[jj] = f2b(tile[c8 + jj][r]);
      *(uint4*)&out[(size_t)(n0 + r) * K + k0 + c8] = *(const uint4*)tmp;
    }
  } else {
    // ----- ln1 (fp32 in, bf16 out), row = blockIdx.x - 3072, C = 1024 -----
    const int row = blockIdx.x - 3072;
    const int wave = tid >> 6, lane = tid & 63;
    const int base = tid * 4;
    float4 v = *(const float4*)&xv[(size_t)row * 1024 + base];
    float f[4] = {v.x, v.y, v.z, v.w};
    float s = f[0] + f[1] + f[2] + f[3];
    float q = f[0] * f[0] + f[1] * f[1] + f[2] * f[2] + f[3] * f[3];
#pragma unroll
    for (int off = 1; off < 64; off <<= 1) {
      s += __shfl_xor(s, off);
      q += __shfl_xor(q, off);
    }
    __shared__ float reds[4], redq[4];
    if (lane == 0) { reds[wave] = s; redq[wave] = q; }
    __syncthreads();
    float S = reds[0] + reds[1] + reds[2] + reds[3];
    float Q = redq[0] + redq[1] + redq[2] + redq[3];
    const float inv = 1.0f / 1024.0f;
    float mean = S * inv;
    float var = Q * inv - mean * mean;
    float rs = rsqrtf(var + 1e-5f);
    float4 gv = *(const float4*)&g[base];
    float4 bv = *(const float4*)&bb[base];
    ushort4 ov;
    ov.x = f2b((f[0] - mean) * rs * gv.x + bv.x);
    ov.y = f2b((f[1] - mean) * rs * gv.y + bv.y);
    ov.z = f2b((f[2] - mean) * rs * gv.z + bv.z);
    ov.w = f2b((f[3] - mean) * rs * gv.w + bv.w);
    *(ushort4*)&o[(size_t)row * 1024 + base] = ov;
  }
}

// ------- LayerNorm (bf16 in): one block per row, C = 1024 --------------------------
__global__ __launch_bounds__(256) void ln_kernel(const u16* __restrict__ xv,
                                                 const float* __restrict__ g,
                                                 const float* __restrict__ b,
                                                 u16* __restrict__ o) {
  const int row = blockIdx.x, tid = threadIdx.x;
  const int wave = tid >> 6, lane = tid & 63;
  const int base = tid * 4;
  ushort4 v = *(const ushort4*)&xv[(size_t)row * 1024 + base];
  float f[4] = {b2f(v.x), b2f(v.y), b2f(v.z), b2f(v.w)};
  float s = f[0] + f[1] + f[2] + f[3];
  float q = f[0] * f[0] + f[1] * f[1] + f[2] * f[2] + f[3] * f[3];
#pragma unroll
  for (int off = 1; off < 64; off <<= 1) {
    s += __shfl_xor(s, off);
    q += __shfl_xor(q, off);
  }
  __shared__ float reds[4], redq[4];
  if (lane == 0) { reds[wave] = s; redq[wave] = q; }
  __syncthreads();
  float S = reds[0] + reds[1] + reds[2] + reds[3];
  float Q = redq[0] + redq[1] + redq[2] + redq[3];
  const float inv = 1.0f / 1024.0f;
  float mean = S * inv;
  float var = Q * inv - mean * mean;
  float rs = rsqrtf(var + 1e-5f);
  float4 gv = *(const float4*)&g[base];
  float4 bv = *(const float4*)&b[base];
  ushort4 ov;
  ov.x = f2b((f[0] - mean) * rs * gv.x + bv.x);
  ov.y = f2b((f[1] - mean) * rs * gv.y + bv.y);
  ov.z = f2b((f[2] - mean) * rs * gv.z + bv.z);
  ov.w = f2b((f[3] - mean) * rs * gv.w + bv.w);
  *(ushort4*)&o[(size_t)row * 1024 + base] = ov;
}

// fast tanh-GELU: 0.5x(1+tanh(a)) == x * sigmoid(2a) == x / (1 + 2^(-2a*log2e)).
__device__ __forceinline__ float gelu_fn(float v) {
  float a = 0.7978845608028654f * __builtin_fmaf(0.044715f * v * v, v, v);
  float t = __builtin_amdgcn_exp2f(a * -2.8853900817779268f);  // 2^(-2a*log2e)
  return v * __builtin_amdgcn_rcpf(1.0f + t);
}

// ------- GEMM 128^2 tile, 2-barrier m97 structure, 8 waves (R12/R13) ---------------
// 512 thr / 8 waves, per-wave 32x64 out; wave cap 32/CU (vs 20 at 256-thr).
// VSPLIT (qkv only): output cols >= 2048 (V slice) written TRANSPOSED into
// vt[bh][dim][token]; a thread's 4 acc rows = 4 consecutive tokens = one ushort4.
// RESMODE: 0 none, 1 bf16 res, 2 fp32 res. OUTF32: write fp32 else bf16.
template <bool GELU, int RESMODE, bool OUTF32, bool VSPLIT>
__global__ __launch_bounds__(512, 4) void gemm8_kernel(const u16* __restrict__ A,
                                                       const u16* __restrict__ Bt,
                                                       const float* __restrict__ bias,
                                                       const void* __restrict__ res,
                                                       void* __restrict__ Cv,
                                                       u16* __restrict__ vt,
                                                       int M, int N, int K) {
  __shared__ u16 As[128 * 64];
  __shared__ u16 Bs[128 * 64];
  const int tid = threadIdx.x;
  const int wave = tid >> 6, lane = tid & 63;
  const int lhi = lane >> 4, llo = lane & 15;
  const int sw = llo & 7;  // wr/wc multiples of 16 -> row&7 == llo&7 for fragment rows
  const int m0 = blockIdx.x * 128, n0 = blockIdx.y * 128;
  const int wr = (wave & 3) * 32, wc = (wave >> 2) * 64;

  f32x4 acc[2][4] = {};

  for (int k0 = 0; k0 < K; k0 += 64) {
#pragma unroll
    for (int p = 0; p < 2; ++p) {
      int s = p * 512 + tid;             // 16B-chunk 0..1023 (128 rows x 8)
      int r = s >> 3;
      int c = ((s & 7) ^ (r & 7)) * 8;   // source k-offset (u16), swizzle-inverted
      GLOAD_LDS16(A + (size_t)(m0 + r) * K + k0 + c, As + s * 8);
      GLOAD_LDS16(Bt + (size_t)(n0 + r) * K + k0 + c, Bs + s * 8);
    }
    __syncthreads();
#pragma unroll
    for (int kk = 0; kk < 2; ++kk) {
      const int cp = ((kk * 4 + lhi) ^ sw) * 8;
      bf16x8 af[2], bf[4];
#pragma unroll
      for (int i = 0; i < 2; ++i)
        af[i] = *(const bf16x8*)&As[(wr + i * 16 + llo) * 64 + cp];
#pragma unroll
      for (int j = 0; j < 4; ++j)
        bf[j] = *(const bf16x8*)&Bs[(wc + j * 16 + llo) * 64 + cp];
#pragma unroll
      for (int i = 0; i < 2; ++i)
#pragma unroll
        for (int j = 0; j < 4; ++j)
          acc[i][j] = __builtin_amdgcn_mfma_f32_16x16x32_bf16(af[i], bf[j], acc[i][j], 0, 0, 0);
    }
    __syncthreads();
  }

  const bool vblock = VSPLIT && (n0 >= 2048);
#pragma unroll
  for (int i = 0; i < 2; ++i) {
    int row = m0 + wr + i * 16 + lhi * 4;
#pragma unroll
    for (int j = 0; j < 4; ++j) {
      int col = n0 + wc + j * 16 + llo;
      float bv = bias[col];
      if (vblock) {
        // V slice -> vt[bh][d][t]; 4 consecutive rows (=tokens) -> one ushort4
        const int hcol = col - 2048;
        const int bh = (row >> 11) * 16 + (hcol >> 6);
        const int d = hcol & 63;
        const int t = row & 2047;
        ushort4 tv;
        tv.x = f2b(acc[i][j][0] + bv);
        tv.y = f2b(acc[i][j][1] + bv);
        tv.z = f2b(acc[i][j][2] + bv);
        tv.w = f2b(acc[i][j][3] + bv);
        *(ushort4*)&vt[((size_t)bh * 64 + d) * 2048 + t] = tv;
        continue;
      }
#pragma unroll
      for (int r = 0; r < 4; ++r) {
        float v = acc[i][j][r] + bv;
        if (GELU) v = gelu_fn(v);
        size_t idx = (size_t)(row + r) * N + col;
        if (RESMODE == 1) v += b2f(((const u16*)res)[idx]);
        if (RESMODE == 2) v += ((const float*)res)[idx];
        if (OUTF32) ((float*)Cv)[idx] = v;
        else ((u16*)Cv)[idx] = f2b(v);
      }
    }
  }
}

// ------- Flash attention (R14: double-buffered K/V -> ONE barrier per ktile) --------
// Block = qtile pair (15-i, i), 128 q rows each, uniform 34 ktiles, 512 thr / 8 waves,
// each wave owns one 16-row q-subtile. R13 profile: MfmaUtil 17 / VALU 38 / HBM 25 --
// latency-bound on the serial per-tile chain with 2 barriers each. Double buffering:
// iteration kt stages tile kt+1 into buf[(kt+1)&1] while computing tile kt from
// buf[kt&1]; the single end-of-iteration barrier guarantees (a) staging kt+1 visible
// before kt+1 reads, (b) reads of tile kt done before iteration kt+1 stages tile kt+2
// into buf[kt&1]. Barriers 68 -> 34 per block. LDS 52KB -> still 2 blocks/CU.
// + s_setprio(1) around MFMA clusters (m191: +4-7% attn in this regime).
__global__ __launch_bounds__(512, 4) void attn_kernel(const u16* __restrict__ qkv,
                                                      const u16* __restrict__ vt,
                                                      u16* __restrict__ out) {
  __shared__ u16 Ks[2][64 * 68];  // [buf][key][dim]
  __shared__ u16 Vs[2][64 * 68];  // [buf][dim][key] (pre-transposed in vt)
  __shared__ u16 Ps[128 * 68];    // per-wave 16-row regions
  const int tid = threadIdx.x;
  const int wave = tid >> 6, lane = tid & 63;  // wave 0..7
  const int lhi = lane >> 4, llo = lane & 15;
  const int pr = blockIdx.x;  // pair index 0..7
  const int bh = blockIdx.y;
  const int b = bh >> 4, h = bh & 15;
  const size_t rowbase = (size_t)b * 2048;
  const int qoff = h * 64, koff = 1024 + h * 64;
  const u16* vtb = vt + (size_t)bh * 64 * 2048;
  const int sr = tid >> 3;       // staging row (0..63)
  const int sc = (tid & 7) * 8;  // staging col

#pragma unroll
  for (int ph = 0; ph < 2; ++ph) {
    const int qtile = ph ? pr : (15 - pr);
    const int q0 = qtile * 128;
    const int qrow = q0 + wave * 16;  // this wave's 16-row subtile

    // Q fragments -> registers for this phase
    bf16x8 qf[2];
#pragma unroll
    for (int kk = 0; kk < 2; ++kk) {
      uint4 v = *(const uint4*)&qkv[(rowbase + qrow + llo) * 3072 + qoff + kk * 32 + lhi * 8];
      qf[kk] = *(const bf16x8*)&v;
    }

    f32x4 oacc[4] = {};
    float l_st[4] = {};
    const int nkt = 2 * qtile + 2;

    // prologue: tile 0 -> buf0, prefetch tile 1 regs, one barrier
    {
      uint4 k0 = *(const uint4*)&qkv[(rowbase + sr) * 3072 + koff + sc];
      uint4 v0 = *(const uint4*)&vtb[(size_t)sr * 2048 + sc];
      *(uint4*)&Ks[0][sr * 68 + sc] = k0;
      *(uint4*)&Vs[0][sr * 68 + sc] = v0;
    }
    uint4 pk, pv;
    if (nkt > 1) {
      pk = *(const uint4*)&qkv[(rowbase + 64 + sr) * 3072 + koff + sc];
      pv = *(const uint4*)&vtb[(size_t)sr * 2048 + 64 + sc];
    }
    __syncthreads();  // tile 0 visible

    for (int kt = 0; kt < nkt; ++kt) {
      const int kt0 = kt * 64;
      const int cur = kt & 1;
      // stage tile kt+1 into the other buffer (its last readers finished at kt-1's barrier)
      if (kt + 1 < nkt) {
        *(uint4*)&Ks[cur ^ 1][sr * 68 + sc] = pk;
        *(uint4*)&Vs[cur ^ 1][sr * 68 + sc] = pv;
        if (kt + 2 < nkt) {
          const int nt0 = kt0 + 128;
          pk = *(const uint4*)&qkv[(rowbase + nt0 + sr) * 3072 + koff + sc];
          pv = *(const uint4*)&vtb[(size_t)sr * 2048 + nt0 + sc];
        }
      }

      // wave-uniform skip of fully-masked subtiles (barrier below still uniform)
      if (kt0 <= qrow + 15) {
        // S = Q K^T for this wave's 16 rows
        f32x4 s[4] = {};
        __builtin_amdgcn_s_setprio(1);
#pragma unroll
        for (int kk = 0; kk < 2; ++kk)
#pragma unroll
          for (int j = 0; j < 4; ++j) {
            bf16x8 kf = *(const bf16x8*)&Ks[cur][(j * 16 + llo) * 68 + kk * 32 + lhi * 8];
            s[j] = __builtin_amdgcn_mfma_f32_16x16x32_bf16(qf[kk], kf, s[j], 0, 0, 0);
          }
        __builtin_amdgcn_s_setprio(0);

        // static-max softmax; P -> this wave's LDS region
        const bool msk = (kt0 + 63 > qrow);
        u16* psrow = &Ps[(wave * 16) * 68];
#pragma unroll
        for (int j = 0; j < 4; ++j) {
          const int key = kt0 + j * 16 + llo;
#pragma unroll
          for (int r = 0; r < 4; ++r) {
            float sv = s[j][r];
            if (msk) sv = (key <= qrow + lhi * 4 + r) ? sv : -1e30f;
            float p = __builtin_amdgcn_exp2f(__builtin_fmaf(sv, SC_LOG2E, -MB_LOG2E));
            l_st[r] += p;
            psrow[(lhi * 4 + r) * 68 + j * 16 + llo] = (u16)(__float_as_uint(p) >> 16);
          }
        }

        // O += P V   (same-wave DS ordering; no barrier needed before readback)
        __builtin_amdgcn_s_setprio(1);
#pragma unroll
        for (int kc = 0; kc < 2; ++kc) {
          bf16x8 pf = *(const bf16x8*)&Ps[(wave * 16 + llo) * 68 + kc * 32 + lhi * 8];
#pragma unroll
          for (int j4 = 0; j4 < 4; ++j4) {
            bf16x8 vf = *(const bf16x8*)&Vs[cur][(j4 * 16 + llo) * 68 + kc * 32 + lhi * 8];
            oacc[j4] = __builtin_amdgcn_mfma_f32_16x16x32_bf16(pf, vf, oacc[j4], 0, 0, 0);
          }
        }
        __builtin_amdgcn_s_setprio(0);
      }

      __syncthreads();  // staging kt+1 visible; readers of tile kt done
    }

    // reduce l across the 16 llo lanes once, then scale + store
#pragma unroll
    for (int r = 0; r < 4; ++r) {
      float v = l_st[r];
      v += __shfl_xor(v, 1);
      v += __shfl_xor(v, 2);
      v += __shfl_xor(v, 4);
      v += __shfl_xor(v, 8);
      l_st[r] = 1.0f / v;
    }
#pragma unroll
    for (int j4 = 0; j4 < 4; ++j4)
#pragma unroll
      for (int r = 0; r < 4; ++r) {
        size_t row = rowbase + qrow + lhi * 4 + r;
        out[row * 1024 + h * 64 + j4 * 16 + llo] = f2b(oacc[j4][r] * l_st[r]);
      }
  }
}

extern "C" void kernel_launch(void* const* d_in, const int* in_sizes, int n_in,
                              void* d_out, int out_size, void* d_ws, size_t ws_size,
                              hipStream_t stream) {
  // All reference tensors are float32.
  const float* x        = (const float*)d_in[0];
  const float* c_attn_w = (const float*)d_in[1];
  const float* c_attn_b = (const float*)d_in[2];
  const float* c_proj_w = (const float*)d_in[3];
  const float* c_proj_b = (const float*)d_in[4];
  const float* fc_w     = (const float*)d_in[5];
  const float* fc_b     = (const float*)d_in[6];
  const float* proj_w   = (const float*)d_in[7];
  const float* proj_b   = (const float*)d_in[8];
  const float* ln1_g    = (const float*)d_in[9];
  const float* ln1_b    = (const float*)d_in[10];
  const float* ln2_g    = (const float*)d_in[11];
  const float* ln2_b    = (const float*)d_in[12];
  float* out = (float*)d_out;  // fp32 output
  u16* ws = (u16*)d_ws;

  // workspace layout (u16 elements)
  const size_t M = 8192;
  u16* ln_buf = ws;                  // 8192*1024  (also reused as attention output)
  u16* qkv    = ln_buf + M * 1024;   // 8192*3072
  u16* x1     = qkv + M * 3072;      // 8192*1024
  u16* hbuf   = x1 + M * 1024;       // 8192*4096 (aliased: vt during attention)
  u16* wT_a   = hbuf + M * 4096;     // 3072*1024
  u16* wT_p   = wT_a + 3072 * 1024;  // 1024*1024
  u16* wT_f   = wT_p + 1024 * 1024;  // 4096*1024
  u16* wT_m   = wT_f + 4096 * 1024;  // 1024*4096
  u16* vt     = hbuf;                // 64*64*2048 u16; dead before FC GEMM

  // prep: 4 weight transposes + ln1 in ONE launch
  TJob ja = {c_attn_w, wT_a, 1024, 3072, 48, 48 * 16};
  TJob jp = {c_proj_w, wT_p, 1024, 1024, 16, 16 * 16};
  TJob jf = {fc_w,     wT_f, 1024, 4096, 64, 64 * 16};
  TJob jm = {proj_w,   wT_m, 4096, 1024, 16, 16 * 64};
  prep_kernel<<<dim3(3072 + 8192), dim3(256), 0, stream>>>(ja, jp, jf, jm, x, ln1_g, ln1_b, ln_buf);

  // qkv GEMM with fused V-transpose: V slice (cols 2048..3071) lands directly in vt
  gemm8_kernel<false, 0, false, true><<<dim3(64, 24), dim3(512), 0, stream>>>(ln_buf, wT_a, c_attn_b, nullptr, qkv, vt, 8192, 3072, 1024);
  attn_kernel<<<dim3(8, 64), dim3(512), 0, stream>>>(qkv, vt, ln_buf);
  gemm8_kernel<false, 2, false, false><<<dim3(64, 8), dim3(512), 0, stream>>>(ln_buf, wT_p, c_proj_b, x, x1, nullptr, 8192, 1024, 1024);
  ln_kernel<<<8192, dim3(256), 0, stream>>>(x1, ln2_g, ln2_b, ln_buf);
  gemm8_kernel<true, 0, false, false><<<dim3(64, 32), dim3(512), 0, stream>>>(ln_buf, wT_f, fc_b, nullptr, hbuf, nullptr, 8192, 4096, 1024);
  gemm8_kernel<false, 1, true, false><<<dim3(64, 8), dim3(512), 0, stream>>>(hbuf, wT_m, proj_b, x1, out, nullptr, 8192, 1024, 4096);
}

// Round 15
// 458.705 us; speedup vs baseline: 1.0013x; 1.0013x over previous
//
#include <hip/hip_runtime.h>

typedef unsigned short u16;
typedef __attribute__((ext_vector_type(8))) short bf16x8;
typedef __attribute__((ext_vector_type(4))) float f32x4;

#define SC_LOG2E 0.18033688011112043f  // 0.125 * log2(e)
#define MB_LOG2E 17.31234049066756f    // 12 * log2(e)  (static softmax max; logits hard-bounded << 88)

__device__ __forceinline__ float b2f(u16 u) {
  union { unsigned int i; float f; } v; v.i = ((unsigned int)u) << 16; return v.f;
}
__device__ __forceinline__ u16 f2b(float f) {
  unsigned int x = __float_as_uint(f);
  unsigned int r = (x + 0x7fffu + ((x >> 16) & 1u)) >> 16;
  return (u16)r;
}

// async global->LDS, 16B per lane; lds base must be wave-uniform, lane l lands at base + l*16
#define GLOAD_LDS16(g, l)                                                              \
  __builtin_amdgcn_global_load_lds((const __attribute__((address_space(1))) void*)(g), \
                                   (__attribute__((address_space(3))) void*)(l), 16, 0, 0)

// ------- prep: 4 weight transposes + LayerNorm1, ONE launch -------------------------
// blocks [0,3072): transpose jobs; [3072,11264): ln1 rows. Per-block uniform branch.
struct TJob { const float* in; u16* out; int K, N, nbx, nblocks; };

__global__ __launch_bounds__(256) void prep_kernel(TJob j0, TJob j1, TJob j2, TJob j3,
                                                   const float* __restrict__ xv,
                                                   const float* __restrict__ g,
                                                   const float* __restrict__ bb,
                                                   u16* __restrict__ o) {
  const int tid = threadIdx.x;
  if (blockIdx.x < 3072) {
    int bid = blockIdx.x;
    TJob j = j0;
    if (bid >= j.nblocks) { bid -= j.nblocks; j = j1; }
    if (bid >= j.nblocks) { bid -= j.nblocks; j = j2; }
    if (bid >= j.nblocks) { bid -= j.nblocks; j = j3; }
    const int n0 = (bid % j.nbx) * 64, k0 = (bid / j.nbx) * 64;
    const int N = j.N, K = j.K;
    const float* __restrict__ in = j.in;
    u16* __restrict__ out = j.out;

    __shared__ float tile[64][65];
#pragma unroll
    for (int it = 0; it < 4; ++it) {
      int lin = it * 256 + tid;
      int r = lin >> 4, c4 = (lin & 15) * 4;
      float4 v = *(const float4*)&in[(size_t)(k0 + r) * N + n0 + c4];
      tile[r][c4 + 0] = v.x; tile[r][c4 + 1] = v.y;
      tile[r][c4 + 2] = v.z; tile[r][c4 + 3] = v.w;
    }
    __syncthreads();
#pragma unroll
    for (int it = 0; it < 2; ++it) {
      int lin = it * 256 + tid;
      int r = lin >> 3, c8 = (lin & 7) * 8;  // r = n-index, c8 = k-block
      u16 tmp[8];
#pragma unroll
      for (int jj = 0; jj < 8; ++jj) tmp[jj] = f2b(tile[c8 + jj][r]);
      *(uint4*)&out[(size_t)(n0 + r) * K + k0 + c8] = *(const uint4*)tmp;
    }
  } else {
    // ----- ln1 (fp32 in, bf16 out), row = blockIdx.x - 3072, C = 1024 -----
    const int row = blockIdx.x - 3072;
    const int wave = tid >> 6, lane = tid & 63;
    const int base = tid * 4;
    float4 v = *(const float4*)&xv[(size_t)row * 1024 + base];
    float f[4] = {v.x, v.y, v.z, v.w};
    float s = f[0] + f[1] + f[2] + f[3];
    float q = f[0] * f[0] + f[1] * f[1] + f[2] * f[2] + f[3] * f[3];
#pragma unroll
    for (int off = 1; off < 64; off <<= 1) {
      s += __shfl_xor(s, off);
      q += __shfl_xor(q, off);
    }
    __shared__ float reds[4], redq[4];
    if (lane == 0) { reds[wave] = s; redq[wave] = q; }
    __syncthreads();
    float S = reds[0] + reds[1] + reds[2] + reds[3];
    float Q = redq[0] + redq[1] + redq[2] + redq[3];
    const float inv = 1.0f / 1024.0f;
    float mean = S * inv;
    float var = Q * inv - mean * mean;
    float rs = rsqrtf(var + 1e-5f);
    float4 gv = *(const float4*)&g[base];
    float4 bv = *(const float4*)&bb[base];
    ushort4 ov;
    ov.x = f2b((f[0] - mean) * rs * gv.x + bv.x);
    ov.y = f2b((f[1] - mean) * rs * gv.y + bv.y);
    ov.z = f2b((f[2] - mean) * rs * gv.z + bv.z);
    ov.w = f2b((f[3] - mean) * rs * gv.w + bv.w);
    *(ushort4*)&o[(size_t)row * 1024 + base] = ov;
  }
}

// ------- LayerNorm (bf16 in): one block per row, C = 1024 --------------------------
__global__ __launch_bounds__(256) void ln_kernel(const u16* __restrict__ xv,
                                                 const float* __restrict__ g,
                                                 const float* __restrict__ b,
                                                 u16* __restrict__ o) {
  const int row = blockIdx.x, tid = threadIdx.x;
  const int wave = tid >> 6, lane = tid & 63;
  const int base = tid * 4;
  ushort4 v = *(const ushort4*)&xv[(size_t)row * 1024 + base];
  float f[4] = {b2f(v.x), b2f(v.y), b2f(v.z), b2f(v.w)};
  float s = f[0] + f[1] + f[2] + f[3];
  float q = f[0] * f[0] + f[1] * f[1] + f[2] * f[2] + f[3] * f[3];
#pragma unroll
  for (int off = 1; off < 64; off <<= 1) {
    s += __shfl_xor(s, off);
    q += __shfl_xor(q, off);
  }
  __shared__ float reds[4], redq[4];
  if (lane == 0) { reds[wave] = s; redq[wave] = q; }
  __syncthreads();
  float S = reds[0] + reds[1] + reds[2] + reds[3];
  float Q = redq[0] + redq[1] + redq[2] + redq[3];
  const float inv = 1.0f / 1024.0f;
  float mean = S * inv;
  float var = Q * inv - mean * mean;
  float rs = rsqrtf(var + 1e-5f);
  float4 gv = *(const float4*)&g[base];
  float4 bv = *(const float4*)&b[base];
  ushort4 ov;
  ov.x = f2b((f[0] - mean) * rs * gv.x + bv.x);
  ov.y = f2b((f[1] - mean) * rs * gv.y + bv.y);
  ov.z = f2b((f[2] - mean) * rs * gv.z + bv.z);
  ov.w = f2b((f[3] - mean) * rs * gv.w + bv.w);
  *(ushort4*)&o[(size_t)row * 1024 + base] = ov;
}

// fast tanh-GELU: 0.5x(1+tanh(a)) == x * sigmoid(2a) == x / (1 + 2^(-2a*log2e)).
__device__ __forceinline__ float gelu_fn(float v) {
  float a = 0.7978845608028654f * __builtin_fmaf(0.044715f * v * v, v, v);
  float t = __builtin_amdgcn_exp2f(a * -2.8853900817779268f);  // 2^(-2a*log2e)
  return v * __builtin_amdgcn_rcpf(1.0f + t);
}

// ------- GEMM 128^2 tile, 2-barrier m97 structure, 8 waves (R12/R13) ---------------
// 512 thr / 8 waves, per-wave 32x64 out; wave cap 32/CU (vs 20 at 256-thr).
// VSPLIT (qkv only): output cols >= 2048 (V slice) written TRANSPOSED into
// vt[bh][dim][token]; a thread's 4 acc rows = 4 consecutive tokens = one ushort4.
// RESMODE: 0 none, 1 bf16 res, 2 fp32 res. OUTF32: write fp32 else bf16.
template <bool GELU, int RESMODE, bool OUTF32, bool VSPLIT>
__global__ __launch_bounds__(512, 4) void gemm8_kernel(const u16* __restrict__ A,
                                                       const u16* __restrict__ Bt,
                                                       const float* __restrict__ bias,
                                                       const void* __restrict__ res,
                                                       void* __restrict__ Cv,
                                                       u16* __restrict__ vt,
                                                       int M, int N, int K) {
  __shared__ u16 As[128 * 64];
  __shared__ u16 Bs[128 * 64];
  const int tid = threadIdx.x;
  const int wave = tid >> 6, lane = tid & 63;
  const int lhi = lane >> 4, llo = lane & 15;
  const int sw = llo & 7;  // wr/wc multiples of 16 -> row&7 == llo&7 for fragment rows
  const int m0 = blockIdx.x * 128, n0 = blockIdx.y * 128;
  const int wr = (wave & 3) * 32, wc = (wave >> 2) * 64;

  f32x4 acc[2][4] = {};

  for (int k0 = 0; k0 < K; k0 += 64) {
#pragma unroll
    for (int p = 0; p < 2; ++p) {
      int s = p * 512 + tid;             // 16B-chunk 0..1023 (128 rows x 8)
      int r = s >> 3;
      int c = ((s & 7) ^ (r & 7)) * 8;   // source k-offset (u16), swizzle-inverted
      GLOAD_LDS16(A + (size_t)(m0 + r) * K + k0 + c, As + s * 8);
      GLOAD_LDS16(Bt + (size_t)(n0 + r) * K + k0 + c, Bs + s * 8);
    }
    __syncthreads();
#pragma unroll
    for (int kk = 0; kk < 2; ++kk) {
      const int cp = ((kk * 4 + lhi) ^ sw) * 8;
      bf16x8 af[2], bf[4];
#pragma unroll
      for (int i = 0; i < 2; ++i)
        af[i] = *(const bf16x8*)&As[(wr + i * 16 + llo) * 64 + cp];
#pragma unroll
      for (int j = 0; j < 4; ++j)
        bf[j] = *(const bf16x8*)&Bs[(wc + j * 16 + llo) * 64 + cp];
#pragma unroll
      for (int i = 0; i < 2; ++i)
#pragma unroll
        for (int j = 0; j < 4; ++j)
          acc[i][j] = __builtin_amdgcn_mfma_f32_16x16x32_bf16(af[i], bf[j], acc[i][j], 0, 0, 0);
    }
    __syncthreads();
  }

  const bool vblock = VSPLIT && (n0 >= 2048);
#pragma unroll
  for (int i = 0; i < 2; ++i) {
    int row = m0 + wr + i * 16 + lhi * 4;
#pragma unroll
    for (int j = 0; j < 4; ++j) {
      int col = n0 + wc + j * 16 + llo;
      float bv = bias[col];
      if (vblock) {
        // V slice -> vt[bh][d][t]; 4 consecutive rows (=tokens) -> one ushort4
        const int hcol = col - 2048;
        const int bh = (row >> 11) * 16 + (hcol >> 6);
        const int d = hcol & 63;
        const int t = row & 2047;
        ushort4 tv;
        tv.x = f2b(acc[i][j][0] + bv);
        tv.y = f2b(acc[i][j][1] + bv);
        tv.z = f2b(acc[i][j][2] + bv);
        tv.w = f2b(acc[i][j][3] + bv);
        *(ushort4*)&vt[((size_t)bh * 64 + d) * 2048 + t] = tv;
        continue;
      }
#pragma unroll
      for (int r = 0; r < 4; ++r) {
        float v = acc[i][j][r] + bv;
        if (GELU) v = gelu_fn(v);
        size_t idx = (size_t)(row + r) * N + col;
        if (RESMODE == 1) v += b2f(((const u16*)res)[idx]);
        if (RESMODE == 2) v += ((const float*)res)[idx];
        if (OUTF32) ((float*)Cv)[idx] = v;
        else ((u16*)Cv)[idx] = f2b(v);
      }
    }
  }
}

// ------- Flash attention (R13 structure + setprio ONLY, R15) ------------------------
// Block = qtile pair (15-i, i), 128 q rows each, uniform 34 ktiles, 512 thr / 8 waves,
// each wave owns one 16-row q-subtile -> 2 blocks/CU = 16 waves/CU. R14's dbuf change
// was neutral-to-negative and bundled two variables; this round isolates s_setprio(1)
// around the MFMA clusters (m191: +4-7% attn when independent blocks co-resident).
__global__ __launch_bounds__(512, 4) void attn_kernel(const u16* __restrict__ qkv,
                                                      const u16* __restrict__ vt,
                                                      u16* __restrict__ out) {
  __shared__ u16 Ks[64 * 68];   // [key][dim]
  __shared__ u16 Vs[64 * 68];   // [dim][key] (pre-transposed in vt)
  __shared__ u16 Ps[128 * 68];  // per-wave 16-row regions
  const int tid = threadIdx.x;
  const int wave = tid >> 6, lane = tid & 63;  // wave 0..7
  const int lhi = lane >> 4, llo = lane & 15;
  const int pr = blockIdx.x;  // pair index 0..7
  const int bh = blockIdx.y;
  const int b = bh >> 4, h = bh & 15;
  const size_t rowbase = (size_t)b * 2048;
  const int qoff = h * 64, koff = 1024 + h * 64;
  const u16* vtb = vt + (size_t)bh * 64 * 2048;
  const int sr = tid >> 3;       // staging row (0..63)
  const int sc = (tid & 7) * 8;  // staging col

#pragma unroll
  for (int ph = 0; ph < 2; ++ph) {
    const int qtile = ph ? pr : (15 - pr);
    const int q0 = qtile * 128;
    const int qrow = q0 + wave * 16;  // this wave's 16-row subtile

    // Q fragments -> registers for this phase
    bf16x8 qf[2];
#pragma unroll
    for (int kk = 0; kk < 2; ++kk) {
      uint4 v = *(const uint4*)&qkv[(rowbase + qrow + llo) * 3072 + qoff + kk * 32 + lhi * 8];
      qf[kk] = *(const bf16x8*)&v;
    }

    f32x4 oacc[4] = {};
    float l_st[4] = {};
    const int nkt = 2 * qtile + 2;

    // prefetch ktile 0 (one uint4 per thread per buffer; 512 threads cover 64x64)
    uint4 pk = *(const uint4*)&qkv[(rowbase + sr) * 3072 + koff + sc];
    uint4 pv = *(const uint4*)&vtb[(size_t)sr * 2048 + sc];

    for (int kt = 0; kt < nkt; ++kt) {
      const int kt0 = kt * 64;
      __syncthreads();  // previous tile's readers done
      *(uint4*)&Ks[sr * 68 + sc] = pk;
      *(uint4*)&Vs[sr * 68 + sc] = pv;
      __syncthreads();  // staging visible
      if (kt + 1 < nkt) {
        const int nt0 = kt0 + 64;
        pk = *(const uint4*)&qkv[(rowbase + nt0 + sr) * 3072 + koff + sc];
        pv = *(const uint4*)&vtb[(size_t)sr * 2048 + nt0 + sc];
      }

      // wave-uniform skip: this wave's subtile fully masked past the diagonal
      if (kt0 > qrow + 15) continue;  // (barriers above already executed uniformly)

      // S = Q K^T for this wave's 16 rows
      f32x4 s[4] = {};
      __builtin_amdgcn_s_setprio(1);
#pragma unroll
      for (int kk = 0; kk < 2; ++kk)
#pragma unroll
        for (int j = 0; j < 4; ++j) {
          bf16x8 kf = *(const bf16x8*)&Ks[(j * 16 + llo) * 68 + kk * 32 + lhi * 8];
          s[j] = __builtin_amdgcn_mfma_f32_16x16x32_bf16(qf[kk], kf, s[j], 0, 0, 0);
        }
      __builtin_amdgcn_s_setprio(0);

      // static-max softmax; P -> this wave's LDS region
      const bool msk = (kt0 + 63 > qrow);
      u16* psrow = &Ps[(wave * 16) * 68];
#pragma unroll
      for (int j = 0; j < 4; ++j) {
        const int key = kt0 + j * 16 + llo;
#pragma unroll
        for (int r = 0; r < 4; ++r) {
          float sv = s[j][r];
          if (msk) sv = (key <= qrow + lhi * 4 + r) ? sv : -1e30f;
          float p = __builtin_amdgcn_exp2f(__builtin_fmaf(sv, SC_LOG2E, -MB_LOG2E));
          l_st[r] += p;
          psrow[(lhi * 4 + r) * 68 + j * 16 + llo] = (u16)(__float_as_uint(p) >> 16);
        }
      }

      // O += P V   (same-wave DS ordering; no barrier needed before readback)
      __builtin_amdgcn_s_setprio(1);
#pragma unroll
      for (int kc = 0; kc < 2; ++kc) {
        bf16x8 pf = *(const bf16x8*)&Ps[(wave * 16 + llo) * 68 + kc * 32 + lhi * 8];
#pragma unroll
        for (int j4 = 0; j4 < 4; ++j4) {
          bf16x8 vf = *(const bf16x8*)&Vs[(j4 * 16 + llo) * 68 + kc * 32 + lhi * 8];
          oacc[j4] = __builtin_amdgcn_mfma_f32_16x16x32_bf16(pf, vf, oacc[j4], 0, 0, 0);
        }
      }
      __builtin_amdgcn_s_setprio(0);
    }

    // reduce l across the 16 llo lanes once, then scale + store
#pragma unroll
    for (int r = 0; r < 4; ++r) {
      float v = l_st[r];
      v += __shfl_xor(v, 1);
      v += __shfl_xor(v, 2);
      v += __shfl_xor(v, 4);
      v += __shfl_xor(v, 8);
      l_st[r] = 1.0f / v;
    }
#pragma unroll
    for (int j4 = 0; j4 < 4; ++j4)
#pragma unroll
      for (int r = 0; r < 4; ++r) {
        size_t row = rowbase + qrow + lhi * 4 + r;
        out[row * 1024 + h * 64 + j4 * 16 + llo] = f2b(oacc[j4][r] * l_st[r]);
      }
  }
}

extern "C" void kernel_launch(void* const* d_in, const int* in_sizes, int n_in,
                              void* d_out, int out_size, void* d_ws, size_t ws_size,
                              hipStream_t stream) {
  // All reference tensors are float32.
  const float* x        = (const float*)d_in[0];
  const float* c_attn_w = (const float*)d_in[1];
  const float* c_attn_b = (const float*)d_in[2];
  const float* c_proj_w = (const float*)d_in[3];
  const float* c_proj_b = (const float*)d_in[4];
  const float* fc_w     = (const float*)d_in[5];
  const float* fc_b     = (const float*)d_in[6];
  const float* proj_w   = (const float*)d_in[7];
  const float* proj_b   = (const float*)d_in[8];
  const float* ln1_g    = (const float*)d_in[9];
  const float* ln1_b    = (const float*)d_in[10];
  const float* ln2_g    = (const float*)d_in[11];
  const float* ln2_b    = (const float*)d_in[12];
  float* out = (float*)d_out;  // fp32 output
  u16* ws = (u16*)d_ws;

  // workspace layout (u16 elements)
  const size_t M = 8192;
  u16* ln_buf = ws;                  // 8192*1024  (also reused as attention output)
  u16* qkv    = ln_buf + M * 1024;   // 8192*3072
  u16* x1     = qkv + M * 3072;      // 8192*1024
  u16* hbuf   = x1 + M * 1024;       // 8192*4096 (aliased: vt during attention)
  u16* wT_a   = hbuf + M * 4096;     // 3072*1024
  u16* wT_p   = wT_a + 3072 * 1024;  // 1024*1024
  u16* wT_f   = wT_p + 1024 * 1024;  // 4096*1024
  u16* wT_m   = wT_f + 4096 * 1024;  // 1024*4096
  u16* vt     = hbuf;                // 64*64*2048 u16; dead before FC GEMM

  // prep: 4 weight transposes + ln1 in ONE launch
  TJob ja = {c_attn_w, wT_a, 1024, 3072, 48, 48 * 16};
  TJob jp = {c_proj_w, wT_p, 1024, 1024, 16, 16 * 16};
  TJob jf = {fc_w,     wT_f, 1024, 4096, 64, 64 * 16};
  TJob jm = {proj_w,   wT_m, 4096, 1024, 16, 16 * 64};
  prep_kernel<<<dim3(3072 + 8192), dim3(256), 0, stream>>>(ja, jp, jf, jm, x, ln1_g, ln1_b, ln_buf);

  // qkv GEMM with fused V-transpose: V slice (cols 2048..3071) lands directly in vt
  gemm8_kernel<false, 0, false, true><<<dim3(64, 24), dim3(512), 0, stream>>>(ln_buf, wT_a, c_attn_b, nullptr, qkv, vt, 8192, 3072, 1024);
  attn_kernel<<<dim3(8, 64), dim3(512), 0, stream>>>(qkv, vt, ln_buf);
  gemm8_kernel<false, 2, false, false><<<dim3(64, 8), dim3(512), 0, stream>>>(ln_buf, wT_p, c_proj_b, x, x1, nullptr, 8192, 1024, 1024);
  ln_kernel<<<8192, dim3(256), 0, stream>>>(x1, ln2_g, ln2_b, ln_buf);
  gemm8_kernel<true, 0, false, false><<<dim3(64, 32), dim3(512), 0, stream>>>(ln_buf, wT_f, fc_b, nullptr, hbuf, nullptr, 8192, 4096, 1024);
  gemm8_kernel<false, 1, true, false><<<dim3(64, 8), dim3(512), 0, stream>>>(hbuf, wT_m, proj_b, x1, out, nullptr, 8192, 1024, 4096);
}

// Round 16
// 441.543 us; speedup vs baseline: 1.0403x; 1.0389x over previous
//
#include <hip/hip_runtime.h>

typedef unsigned short u16;
typedef __attribute__((ext_vector_type(8))) short bf16x8;
typedef __attribute__((ext_vector_type(4))) float f32x4;

#define SC_LOG2E 0.18033688011112043f  // 0.125 * log2(e)
#define MB_LOG2E 17.31234049066756f    // 12 * log2(e)  (static softmax max; logits hard-bounded << 88)

__device__ __forceinline__ float b2f(u16 u) {
  union { unsigned int i; float f; } v; v.i = ((unsigned int)u) << 16; return v.f;
}
__device__ __forceinline__ u16 f2b(float f) {
  unsigned int x = __float_as_uint(f);
  unsigned int r = (x + 0x7fffu + ((x >> 16) & 1u)) >> 16;
  return (u16)r;
}

// async global->LDS, 16B per lane; lds base must be wave-uniform, lane l lands at base + l*16
#define GLOAD_LDS16(g, l)                                                              \
  __builtin_amdgcn_global_load_lds((const __attribute__((address_space(1))) void*)(g), \
                                   (__attribute__((address_space(3))) void*)(l), 16, 0, 0)

// ------- prep: 4 weight transposes + LayerNorm1, ONE launch -------------------------
// blocks [0,3072): transpose jobs; [3072,11264): ln1 rows. Per-block uniform branch.
struct TJob { const float* in; u16* out; int K, N, nbx, nblocks; };

__global__ __launch_bounds__(256) void prep_kernel(TJob j0, TJob j1, TJob j2, TJob j3,
                                                   const float* __restrict__ xv,
                                                   const float* __restrict__ g,
                                                   const float* __restrict__ bb,
                                                   u16* __restrict__ o) {
  const int tid = threadIdx.x;
  if (blockIdx.x < 3072) {
    int bid = blockIdx.x;
    TJob j = j0;
    if (bid >= j.nblocks) { bid -= j.nblocks; j = j1; }
    if (bid >= j.nblocks) { bid -= j.nblocks; j = j2; }
    if (bid >= j.nblocks) { bid -= j.nblocks; j = j3; }
    const int n0 = (bid % j.nbx) * 64, k0 = (bid / j.nbx) * 64;
    const int N = j.N, K = j.K;
    const float* __restrict__ in = j.in;
    u16* __restrict__ out = j.out;

    __shared__ float tile[64][65];
#pragma unroll
    for (int it = 0; it < 4; ++it) {
      int lin = it * 256 + tid;
      int r = lin >> 4, c4 = (lin & 15) * 4;
      float4 v = *(const float4*)&in[(size_t)(k0 + r) * N + n0 + c4];
      tile[r][c4 + 0] = v.x; tile[r][c4 + 1] = v.y;
      tile[r][c4 + 2] = v.z; tile[r][c4 + 3] = v.w;
    }
    __syncthreads();
#pragma unroll
    for (int it = 0; it < 2; ++it) {
      int lin = it * 256 + tid;
      int r = lin >> 3, c8 = (lin & 7) * 8;  // r = n-index, c8 = k-block
      u16 tmp[8];
#pragma unroll
      for (int jj = 0; jj < 8; ++jj) tmp[jj] = f2b(tile[c8 + jj][r]);
      *(uint4*)&out[(size_t)(n0 + r) * K + k0 + c8] = *(const uint4*)tmp;
    }
  } else {
    // ----- ln1 (fp32 in, bf16 out), row = blockIdx.x - 3072, C = 1024 -----
    const int row = blockIdx.x - 3072;
    const int wave = tid >> 6, lane = tid & 63;
    const int base = tid * 4;
    float4 v = *(const float4*)&xv[(size_t)row * 1024 + base];
    float f[4] = {v.x, v.y, v.z, v.w};
    float s = f[0] + f[1] + f[2] + f[3];
    float q = f[0] * f[0] + f[1] * f[1] + f[2] * f[2] + f[3] * f[3];
#pragma unroll
    for (int off = 1; off < 64; off <<= 1) {
      s += __shfl_xor(s, off);
      q += __shfl_xor(q, off);
    }
    __shared__ float reds[4], redq[4];
    if (lane == 0) { reds[wave] = s; redq[wave] = q; }
    __syncthreads();
    float S = reds[0] + reds[1] + reds[2] + reds[3];
    float Q = redq[0] + redq[1] + redq[2] + redq[3];
    const float inv = 1.0f / 1024.0f;
    float mean = S * inv;
    float var = Q * inv - mean * mean;
    float rs = rsqrtf(var + 1e-5f);
    float4 gv = *(const float4*)&g[base];
    float4 bv = *(const float4*)&bb[base];
    ushort4 ov;
    ov.x = f2b((f[0] - mean) * rs * gv.x + bv.x);
    ov.y = f2b((f[1] - mean) * rs * gv.y + bv.y);
    ov.z = f2b((f[2] - mean) * rs * gv.z + bv.z);
    ov.w = f2b((f[3] - mean) * rs * gv.w + bv.w);
    *(ushort4*)&o[(size_t)row * 1024 + base] = ov;
  }
}

// ------- LayerNorm (bf16 in): one block per row, C = 1024 --------------------------
__global__ __launch_bounds__(256) void ln_kernel(const u16* __restrict__ xv,
                                                 const float* __restrict__ g,
                                                 const float* __restrict__ b,
                                                 u16* __restrict__ o) {
  const int row = blockIdx.x, tid = threadIdx.x;
  const int wave = tid >> 6, lane = tid & 63;
  const int base = tid * 4;
  ushort4 v = *(const ushort4*)&xv[(size_t)row * 1024 + base];
  float f[4] = {b2f(v.x), b2f(v.y), b2f(v.z), b2f(v.w)};
  float s = f[0] + f[1] + f[2] + f[3];
  float q = f[0] * f[0] + f[1] * f[1] + f[2] * f[2] + f[3] * f[3];
#pragma unroll
  for (int off = 1; off < 64; off <<= 1) {
    s += __shfl_xor(s, off);
    q += __shfl_xor(q, off);
  }
  __shared__ float reds[4], redq[4];
  if (lane == 0) { reds[wave] = s; redq[wave] = q; }
  __syncthreads();
  float S = reds[0] + reds[1] + reds[2] + reds[3];
  float Q = redq[0] + redq[1] + redq[2] + redq[3];
  const float inv = 1.0f / 1024.0f;
  float mean = S * inv;
  float var = Q * inv - mean * mean;
  float rs = rsqrtf(var + 1e-5f);
  float4 gv = *(const float4*)&g[base];
  float4 bv = *(const float4*)&b[base];
  ushort4 ov;
  ov.x = f2b((f[0] - mean) * rs * gv.x + bv.x);
  ov.y = f2b((f[1] - mean) * rs * gv.y + bv.y);
  ov.z = f2b((f[2] - mean) * rs * gv.z + bv.z);
  ov.w = f2b((f[3] - mean) * rs * gv.w + bv.w);
  *(ushort4*)&o[(size_t)row * 1024 + base] = ov;
}

// fast tanh-GELU: 0.5x(1+tanh(a)) == x * sigmoid(2a) == x / (1 + 2^(-2a*log2e)).
__device__ __forceinline__ float gelu_fn(float v) {
  float a = 0.7978845608028654f * __builtin_fmaf(0.044715f * v * v, v, v);
  float t = __builtin_amdgcn_exp2f(a * -2.8853900817779268f);  // 2^(-2a*log2e)
  return v * __builtin_amdgcn_rcpf(1.0f + t);
}

// ------- GEMM 128^2 tile, 2-barrier m97 structure, 8 waves (R12/R13) ---------------
// 512 thr / 8 waves, per-wave 32x64 out; wave cap 32/CU (vs 20 at 256-thr).
// VSPLIT (qkv only): output cols >= 2048 (V slice) written TRANSPOSED into
// vt[bh][dim][token]; a thread's 4 acc rows = 4 consecutive tokens = one ushort4.
// RESMODE: 0 none, 1 bf16 res, 2 fp32 res. OUTF32: write fp32 else bf16.
template <bool GELU, int RESMODE, bool OUTF32, bool VSPLIT>
__global__ __launch_bounds__(512, 4) void gemm8_kernel(const u16* __restrict__ A,
                                                       const u16* __restrict__ Bt,
                                                       const float* __restrict__ bias,
                                                       const void* __restrict__ res,
                                                       void* __restrict__ Cv,
                                                       u16* __restrict__ vt,
                                                       int M, int N, int K) {
  __shared__ u16 As[128 * 64];
  __shared__ u16 Bs[128 * 64];
  const int tid = threadIdx.x;
  const int wave = tid >> 6, lane = tid & 63;
  const int lhi = lane >> 4, llo = lane & 15;
  const int sw = llo & 7;  // wr/wc multiples of 16 -> row&7 == llo&7 for fragment rows
  const int m0 = blockIdx.x * 128, n0 = blockIdx.y * 128;
  const int wr = (wave & 3) * 32, wc = (wave >> 2) * 64;

  f32x4 acc[2][4] = {};

  for (int k0 = 0; k0 < K; k0 += 64) {
#pragma unroll
    for (int p = 0; p < 2; ++p) {
      int s = p * 512 + tid;             // 16B-chunk 0..1023 (128 rows x 8)
      int r = s >> 3;
      int c = ((s & 7) ^ (r & 7)) * 8;   // source k-offset (u16), swizzle-inverted
      GLOAD_LDS16(A + (size_t)(m0 + r) * K + k0 + c, As + s * 8);
      GLOAD_LDS16(Bt + (size_t)(n0 + r) * K + k0 + c, Bs + s * 8);
    }
    __syncthreads();
#pragma unroll
    for (int kk = 0; kk < 2; ++kk) {
      const int cp = ((kk * 4 + lhi) ^ sw) * 8;
      bf16x8 af[2], bf[4];
#pragma unroll
      for (int i = 0; i < 2; ++i)
        af[i] = *(const bf16x8*)&As[(wr + i * 16 + llo) * 64 + cp];
#pragma unroll
      for (int j = 0; j < 4; ++j)
        bf[j] = *(const bf16x8*)&Bs[(wc + j * 16 + llo) * 64 + cp];
#pragma unroll
      for (int i = 0; i < 2; ++i)
#pragma unroll
        for (int j = 0; j < 4; ++j)
          acc[i][j] = __builtin_amdgcn_mfma_f32_16x16x32_bf16(af[i], bf[j], acc[i][j], 0, 0, 0);
    }
    __syncthreads();
  }

  const bool vblock = VSPLIT && (n0 >= 2048);
#pragma unroll
  for (int i = 0; i < 2; ++i) {
    int row = m0 + wr + i * 16 + lhi * 4;
#pragma unroll
    for (int j = 0; j < 4; ++j) {
      int col = n0 + wc + j * 16 + llo;
      float bv = bias[col];
      if (vblock) {
        // V slice -> vt[bh][d][t]; 4 consecutive rows (=tokens) -> one ushort4
        const int hcol = col - 2048;
        const int bh = (row >> 11) * 16 + (hcol >> 6);
        const int d = hcol & 63;
        const int t = row & 2047;
        ushort4 tv;
        tv.x = f2b(acc[i][j][0] + bv);
        tv.y = f2b(acc[i][j][1] + bv);
        tv.z = f2b(acc[i][j][2] + bv);
        tv.w = f2b(acc[i][j][3] + bv);
        *(ushort4*)&vt[((size_t)bh * 64 + d) * 2048 + t] = tv;
        continue;
      }
#pragma unroll
      for (int r = 0; r < 4; ++r) {
        float v = acc[i][j][r] + bv;
        if (GELU) v = gelu_fn(v);
        size_t idx = (size_t)(row + r) * N + col;
        if (RESMODE == 1) v += b2f(((const u16*)res)[idx]);
        if (RESMODE == 2) v += ((const float*)res)[idx];
        if (OUTF32) ((float*)Cv)[idx] = v;
        else ((u16*)Cv)[idx] = f2b(v);
      }
    }
  }
}

// ------- Flash attention (R16: 2-deep register prefetch) ---------------------------
// R15 structure (single-buffer LDS, 2 barriers/tile, setprio) unchanged; the ONE new
// variable: K/V register prefetch deepened from 1 tile to 2. Mechanism: the tile-kt+1
// load had one tile-compute (~300-500cy) to cover scattered qkv/vt read latency
// (~500-900cy, m126) -> every iteration stalled at the staging vmcnt. Issuing tile
// kt+2's load at iteration kt gives two tile-times of cover. +8 VGPR (56 -> ~64).
__global__ __launch_bounds__(512, 4) void attn_kernel(const u16* __restrict__ qkv,
                                                      const u16* __restrict__ vt,
                                                      u16* __restrict__ out) {
  __shared__ u16 Ks[64 * 68];   // [key][dim]
  __shared__ u16 Vs[64 * 68];   // [dim][key] (pre-transposed in vt)
  __shared__ u16 Ps[128 * 68];  // per-wave 16-row regions
  const int tid = threadIdx.x;
  const int wave = tid >> 6, lane = tid & 63;  // wave 0..7
  const int lhi = lane >> 4, llo = lane & 15;
  const int pr = blockIdx.x;  // pair index 0..7
  const int bh = blockIdx.y;
  const int b = bh >> 4, h = bh & 15;
  const size_t rowbase = (size_t)b * 2048;
  const int qoff = h * 64, koff = 1024 + h * 64;
  const u16* vtb = vt + (size_t)bh * 64 * 2048;
  const int sr = tid >> 3;       // staging row (0..63)
  const int sc = (tid & 7) * 8;  // staging col

#pragma unroll
  for (int ph = 0; ph < 2; ++ph) {
    const int qtile = ph ? pr : (15 - pr);
    const int q0 = qtile * 128;
    const int qrow = q0 + wave * 16;  // this wave's 16-row subtile

    // Q fragments -> registers for this phase
    bf16x8 qf[2];
#pragma unroll
    for (int kk = 0; kk < 2; ++kk) {
      uint4 v = *(const uint4*)&qkv[(rowbase + qrow + llo) * 3072 + qoff + kk * 32 + lhi * 8];
      qf[kk] = *(const bf16x8*)&v;
    }

    f32x4 oacc[4] = {};
    float l_st[4] = {};
    const int nkt = 2 * qtile + 2;  // >= 2 always

    // 2-deep register prefetch: r0 holds tile 0, r1 holds tile 1
    uint4 pk0 = *(const uint4*)&qkv[(rowbase + sr) * 3072 + koff + sc];
    uint4 pv0 = *(const uint4*)&vtb[(size_t)sr * 2048 + sc];
    uint4 pk1 = *(const uint4*)&qkv[(rowbase + 64 + sr) * 3072 + koff + sc];
    uint4 pv1 = *(const uint4*)&vtb[(size_t)sr * 2048 + 64 + sc];

    for (int kt = 0; kt < nkt; ++kt) {
      const int kt0 = kt * 64;
      __syncthreads();  // previous tile's readers done
      if (kt & 1) {
        *(uint4*)&Ks[sr * 68 + sc] = pk1;
        *(uint4*)&Vs[sr * 68 + sc] = pv1;
      } else {
        *(uint4*)&Ks[sr * 68 + sc] = pk0;
        *(uint4*)&Vs[sr * 68 + sc] = pv0;
      }
      __syncthreads();  // staging visible
      if (kt + 2 < nkt) {
        const int nt0 = kt0 + 128;  // tile kt+2: lands two tile-computes from now
        if (kt & 1) {
          pk1 = *(const uint4*)&qkv[(rowbase + nt0 + sr) * 3072 + koff + sc];
          pv1 = *(const uint4*)&vtb[(size_t)sr * 2048 + nt0 + sc];
        } else {
          pk0 = *(const uint4*)&qkv[(rowbase + nt0 + sr) * 3072 + koff + sc];
          pv0 = *(const uint4*)&vtb[(size_t)sr * 2048 + nt0 + sc];
        }
      }

      // wave-uniform skip: this wave's subtile fully masked past the diagonal
      if (kt0 > qrow + 15) continue;  // (barriers above already executed uniformly)

      // S = Q K^T for this wave's 16 rows
      f32x4 s[4] = {};
      __builtin_amdgcn_s_setprio(1);
#pragma unroll
      for (int kk = 0; kk < 2; ++kk)
#pragma unroll
        for (int j = 0; j < 4; ++j) {
          bf16x8 kf = *(const bf16x8*)&Ks[(j * 16 + llo) * 68 + kk * 32 + lhi * 8];
          s[j] = __builtin_amdgcn_mfma_f32_16x16x32_bf16(qf[kk], kf, s[j], 0, 0, 0);
        }
      __builtin_amdgcn_s_setprio(0);

      // static-max softmax; P -> this wave's LDS region
      const bool msk = (kt0 + 63 > qrow);
      u16* psrow = &Ps[(wave * 16) * 68];
#pragma unroll
      for (int j = 0; j < 4; ++j) {
        const int key = kt0 + j * 16 + llo;
#pragma unroll
        for (int r = 0; r < 4; ++r) {
          float sv = s[j][r];
          if (msk) sv = (key <= qrow + lhi * 4 + r) ? sv : -1e30f;
          float p = __builtin_amdgcn_exp2f(__builtin_fmaf(sv, SC_LOG2E, -MB_LOG2E));
          l_st[r] += p;
          psrow[(lhi * 4 + r) * 68 + j * 16 + llo] = (u16)(__float_as_uint(p) >> 16);
        }
      }

      // O += P V   (same-wave DS ordering; no barrier needed before readback)
      __builtin_amdgcn_s_setprio(1);
#pragma unroll
      for (int kc = 0; kc < 2; ++kc) {
        bf16x8 pf = *(const bf16x8*)&Ps[(wave * 16 + llo) * 68 + kc * 32 + lhi * 8];
#pragma unroll
        for (int j4 = 0; j4 < 4; ++j4) {
          bf16x8 vf = *(const bf16x8*)&Vs[(j4 * 16 + llo) * 68 + kc * 32 + lhi * 8];
          oacc[j4] = __builtin_amdgcn_mfma_f32_16x16x32_bf16(pf, vf, oacc[j4], 0, 0, 0);
        }
      }
      __builtin_amdgcn_s_setprio(0);
    }

    // reduce l across the 16 llo lanes once, then scale + store
#pragma unroll
    for (int r = 0; r < 4; ++r) {
      float v = l_st[r];
      v += __shfl_xor(v, 1);
      v += __shfl_xor(v, 2);
      v += __shfl_xor(v, 4);
      v += __shfl_xor(v, 8);
      l_st[r] = 1.0f / v;
    }
#pragma unroll
    for (int j4 = 0; j4 < 4; ++j4)
#pragma unroll
      for (int r = 0; r < 4; ++r) {
        size_t row = rowbase + qrow + lhi * 4 + r;
        out[row * 1024 + h * 64 + j4 * 16 + llo] = f2b(oacc[j4][r] * l_st[r]);
      }
  }
}

extern "C" void kernel_launch(void* const* d_in, const int* in_sizes, int n_in,
                              void* d_out, int out_size, void* d_ws, size_t ws_size,
                              hipStream_t stream) {
  // All reference tensors are float32.
  const float* x        = (const float*)d_in[0];
  const float* c_attn_w = (const float*)d_in[1];
  const float* c_attn_b = (const float*)d_in[2];
  const float* c_proj_w = (const float*)d_in[3];
  const float* c_proj_b = (const float*)d_in[4];
  const float* fc_w     = (const float*)d_in[5];
  const float* fc_b     = (const float*)d_in[6];
  const float* proj_w   = (const float*)d_in[7];
  const float* proj_b   = (const float*)d_in[8];
  const float* ln1_g    = (const float*)d_in[9];
  const float* ln1_b    = (const float*)d_in[10];
  const float* ln2_g    = (const float*)d_in[11];
  const float* ln2_b    = (const float*)d_in[12];
  float* out = (float*)d_out;  // fp32 output
  u16* ws = (u16*)d_ws;

  // workspace layout (u16 elements)
  const size_t M = 8192;
  u16* ln_buf = ws;                  // 8192*1024  (also reused as attention output)
  u16* qkv    = ln_buf + M * 1024;   // 8192*3072
  u16* x1     = qkv + M * 3072;      // 8192*1024
  u16* hbuf   = x1 + M * 1024;       // 8192*4096 (aliased: vt during attention)
  u16* wT_a   = hbuf + M * 4096;     // 3072*1024
  u16* wT_p   = wT_a + 3072 * 1024;  // 1024*1024
  u16* wT_f   = wT_p + 1024 * 1024;  // 4096*1024
  u16* wT_m   = wT_f + 4096 * 1024;  // 1024*4096
  u16* vt     = hbuf;                // 64*64*2048 u16; dead before FC GEMM

  // prep: 4 weight transposes + ln1 in ONE launch
  TJob ja = {c_attn_w, wT_a, 1024, 3072, 48, 48 * 16};
  TJob jp = {c_proj_w, wT_p, 1024, 1024, 16, 16 * 16};
  TJob jf = {fc_w,     wT_f, 1024, 4096, 64, 64 * 16};
  TJob jm = {proj_w,   wT_m, 4096, 1024, 16, 16 * 64};
  prep_kernel<<<dim3(3072 + 8192), dim3(256), 0, stream>>>(ja, jp, jf, jm, x, ln1_g, ln1_b, ln_buf);

  // qkv GEMM with fused V-transpose: V slice (cols 2048..3071) lands directly in vt
  gemm8_kernel<false, 0, false, true><<<dim3(64, 24), dim3(512), 0, stream>>>(ln_buf, wT_a, c_attn_b, nullptr, qkv, vt, 8192, 3072, 1024);
  attn_kernel<<<dim3(8, 64), dim3(512), 0, stream>>>(qkv, vt, ln_buf);
  gemm8_kernel<false, 2, false, false><<<dim3(64, 8), dim3(512), 0, stream>>>(ln_buf, wT_p, c_proj_b, x, x1, nullptr, 8192, 1024, 1024);
  ln_kernel<<<8192, dim3(256), 0, stream>>>(x1, ln2_g, ln2_b, ln_buf);
  gemm8_kernel<true, 0, false, false><<<dim3(64, 32), dim3(512), 0, stream>>>(ln_buf, wT_f, fc_b, nullptr, hbuf, nullptr, 8192, 4096, 1024);
  gemm8_kernel<false, 1, true, false><<<dim3(64, 8), dim3(512), 0, stream>>>(hbuf, wT_m, proj_b, x1, out, nullptr, 8192, 1024, 4096);
}